// Round 1
// baseline (2930.978 us; speedup 1.0000x reference)
//
#include <hip/hip_runtime.h>
#include <math.h>

namespace {

constexpr int Bn = 64;    // batch
constexpr int Cn = 128;   // channels
constexpr int Tn = 512;   // time
constexpr int Hn = 256;   // hidden
constexpr int ROWS = 8;   // rows (t values) per block
constexpr int TBLK = Tn / ROWS;  // 64 blocks along T per batch
constexpr float LN_EPS = 1e-5f;

// Cubic B-spline bases on uniform grid g[j] = 0.4*(j-3) - 1, j=0..11.
// Matches the reference recursion exactly (degree-0 indicator uses >= and <).
__device__ __forceinline__ void bspline8(float x, float bs[8]) {
  float g[12];
#pragma unroll
  for (int j = 0; j < 12; ++j) g[j] = (float)(j - 3) * 0.4f - 1.0f;
  float b0[11];
#pragma unroll
  for (int j = 0; j < 11; ++j) b0[j] = (x >= g[j] && x < g[j + 1]) ? 1.0f : 0.0f;
  float b1[10];
#pragma unroll
  for (int j = 0; j < 10; ++j)
    b1[j] = (x - g[j]) * (1.0f / (g[j + 1] - g[j])) * b0[j] +
            (g[j + 2] - x) * (1.0f / (g[j + 2] - g[j + 1])) * b0[j + 1];
  float b2[9];
#pragma unroll
  for (int j = 0; j < 9; ++j)
    b2[j] = (x - g[j]) * (1.0f / (g[j + 2] - g[j])) * b1[j] +
            (g[j + 3] - x) * (1.0f / (g[j + 3] - g[j + 1])) * b1[j + 1];
#pragma unroll
  for (int j = 0; j < 8; ++j)
    bs[j] = (x - g[j]) * (1.0f / (g[j + 3] - g[j])) * b2[j] +
            (g[j + 4] - x) * (1.0f / (g[j + 4] - g[j + 1])) * b2[j + 1];
}

__device__ __forceinline__ float siluf(float z) {
  return z * (1.0f / (1.0f + expf(-z)));
}

}  // namespace

// ---------------------------------------------------------------------------
// Kernel 1: per-batch mean / rstd over all C*T elements.
// ---------------------------------------------------------------------------
__global__ __launch_bounds__(256) void kan_stats(const float* __restrict__ U,
                                                 float* __restrict__ stats) {
  const int b = blockIdx.x;
  const float* p = U + (size_t)b * (Cn * Tn);
  float s = 0.f, s2 = 0.f;
  for (int i = threadIdx.x; i < Cn * Tn; i += 256) {
    float v = p[i];
    s += v;
    s2 += v * v;
  }
#pragma unroll
  for (int off = 32; off > 0; off >>= 1) {
    s += __shfl_down(s, off);
    s2 += __shfl_down(s2, off);
  }
  __shared__ float red[2][4];
  const int lane = threadIdx.x & 63;
  const int w = threadIdx.x >> 6;
  if (lane == 0) {
    red[0][w] = s;
    red[1][w] = s2;
  }
  __syncthreads();
  if (threadIdx.x == 0) {
    float ts = red[0][0] + red[0][1] + red[0][2] + red[0][3];
    float ts2 = red[1][0] + red[1][1] + red[1][2] + red[1][3];
    const float inv_n = 1.0f / (float)(Cn * Tn);
    float mean = ts * inv_n;
    float var = ts2 * inv_n - mean * mean;
    stats[2 * b + 0] = mean;
    stats[2 * b + 1] = rsqrtf(var + LN_EPS);
  }
}

// ---------------------------------------------------------------------------
// Kernel 2: fused LN -> KAN1 -> KAN2 -> residual, 8 rows (t values) per block.
//
// LDS act layout: s_act[(feat*9 + j)*ROWS + r], j=0..7 spline bases, j=8 silu.
// GEMM phases: each thread owns one output feature; LDS reads are the SAME
// address across the wave -> broadcast (conflict-free), vectorized as float4.
// ---------------------------------------------------------------------------
__global__ __launch_bounds__(256) void kan_fused(
    const float* __restrict__ U, const float* __restrict__ ln_w,
    const float* __restrict__ ln_b, const float* __restrict__ bw1,
    const float* __restrict__ sw1, const float* __restrict__ ss1,
    const float* __restrict__ bw2, const float* __restrict__ sw2,
    const float* __restrict__ ss2, const float* __restrict__ stats,
    float* __restrict__ out) {
  __shared__ float s_act[Cn * 9 * ROWS];  // 36 KB (also reused for act2 halves)
  __shared__ float s_h1[ROWS * Hn];       // 8 KB

  const int tid = threadIdx.x;
  const int blk = blockIdx.x;
  const int b = blk / TBLK;
  const int t0 = (blk % TBLK) * ROWS;
  const float mean = stats[2 * b + 0];
  const float rstd = stats[2 * b + 1];

  // ---- Phase A: LN + act1 (bases + silu) for 8 rows x 128 channels ----
  for (int e = tid; e < Cn * ROWS; e += 256) {
    const int c = e >> 3;
    const int r = e & 7;
    const int t = t0 + r;
    const float u = U[((size_t)b * Cn + c) * Tn + t];
    const float z = (u - mean) * rstd * ln_w[t * Cn + c] + ln_b[t * Cn + c];
    float bs[8];
    bspline8(z, bs);
    float* dst = &s_act[c * 9 * ROWS + r];
#pragma unroll
    for (int j = 0; j < 8; ++j) dst[j * ROWS] = bs[j];
    dst[8 * ROWS] = siluf(z);
  }
  __syncthreads();

  // ---- Phase B: gemm1 — thread owns h = tid, 8 row accumulators ----
  {
    const int h = tid;
    float acc[ROWS] = {0, 0, 0, 0, 0, 0, 0, 0};
    const float4* swp = (const float4*)(sw1 + (size_t)h * Cn * 8);
    const float* ssp = ss1 + (size_t)h * Cn;
    const float* bwp = bw1 + (size_t)h * Cn;
    for (int c = 0; c < Cn; ++c) {
      const float4 w0 = swp[c * 2 + 0];
      const float4 w1 = swp[c * 2 + 1];
      const float sc = ssp[c];
      float w[9];
      w[0] = w0.x * sc; w[1] = w0.y * sc; w[2] = w0.z * sc; w[3] = w0.w * sc;
      w[4] = w1.x * sc; w[5] = w1.y * sc; w[6] = w1.z * sc; w[7] = w1.w * sc;
      w[8] = bwp[c];
      const float4* pa = (const float4*)&s_act[c * 9 * ROWS];
#pragma unroll
      for (int j = 0; j < 9; ++j) {
        const float4 lo = pa[j * 2 + 0];
        const float4 hi = pa[j * 2 + 1];
        acc[0] += lo.x * w[j]; acc[1] += lo.y * w[j];
        acc[2] += lo.z * w[j]; acc[3] += lo.w * w[j];
        acc[4] += hi.x * w[j]; acc[5] += hi.y * w[j];
        acc[6] += hi.z * w[j]; acc[7] += hi.w * w[j];
      }
    }
#pragma unroll
    for (int r = 0; r < ROWS; ++r) s_h1[r * Hn + h] = acc[r];
  }
  __syncthreads();

  // ---- Phases C/D: act2 + gemm2, split into two h-halves (LDS reuse) ----
  const int cc = tid & 127;
  const int rh = tid >> 7;  // 0 or 1 -> rows rh*4 .. rh*4+3
  float acc2[4] = {0, 0, 0, 0};

  for (int half = 0; half < 2; ++half) {
    const int h0 = half * (Hn / 2);
    // act2 for h in [h0, h0+128)
    for (int e = tid; e < (Hn / 2) * ROWS; e += 256) {
      const int hl = e >> 3;
      const int r = e & 7;
      const float z = s_h1[r * Hn + h0 + hl];
      float bs[8];
      bspline8(z, bs);
      float* dst = &s_act[hl * 9 * ROWS + r];
#pragma unroll
      for (int j = 0; j < 8; ++j) dst[j * ROWS] = bs[j];
      dst[8 * ROWS] = siluf(z);
    }
    __syncthreads();

    // gemm2 partial: K over h in this half
    const float4* swp = (const float4*)(sw2 + ((size_t)cc * Hn + h0) * 8);
    const float* ssp = ss2 + (size_t)cc * Hn + h0;
    const float* bwp = bw2 + (size_t)cc * Hn + h0;
    for (int hl = 0; hl < Hn / 2; ++hl) {
      const float4 w0 = swp[hl * 2 + 0];
      const float4 w1 = swp[hl * 2 + 1];
      const float sc = ssp[hl];
      float w[9];
      w[0] = w0.x * sc; w[1] = w0.y * sc; w[2] = w0.z * sc; w[3] = w0.w * sc;
      w[4] = w1.x * sc; w[5] = w1.y * sc; w[6] = w1.z * sc; w[7] = w1.w * sc;
      w[8] = bwp[hl];
      const float* pa = &s_act[hl * 9 * ROWS + rh * 4];
#pragma unroll
      for (int j = 0; j < 9; ++j) {
        const float4 v = *(const float4*)(pa + j * ROWS);
        acc2[0] += v.x * w[j]; acc2[1] += v.y * w[j];
        acc2[2] += v.z * w[j]; acc2[3] += v.w * w[j];
      }
    }
    __syncthreads();  // before act2 of next half overwrites s_act
  }

  // ---- Residual + write: out[b][cc][t0 + rh*4 .. +3] ----
  {
    const size_t base = ((size_t)b * Cn + cc) * Tn + t0 + rh * 4;
    const float4 uin = *(const float4*)(U + base);
    float4 o;
    o.x = uin.x + acc2[0];
    o.y = uin.y + acc2[1];
    o.z = uin.z + acc2[2];
    o.w = uin.w + acc2[3];
    *(float4*)(out + base) = o;
  }
}

extern "C" void kernel_launch(void* const* d_in, const int* in_sizes, int n_in,
                              void* d_out, int out_size, void* d_ws,
                              size_t ws_size, hipStream_t stream) {
  const float* U = (const float*)d_in[0];
  const float* ln_w = (const float*)d_in[1];
  const float* ln_b = (const float*)d_in[2];
  const float* bw1 = (const float*)d_in[3];
  const float* sw1 = (const float*)d_in[4];
  const float* ss1 = (const float*)d_in[5];
  const float* bw2 = (const float*)d_in[6];
  const float* sw2 = (const float*)d_in[7];
  const float* ss2 = (const float*)d_in[8];
  float* out = (float*)d_out;
  float* stats = (float*)d_ws;  // 2 floats per batch

  kan_stats<<<Bn, 256, 0, stream>>>(U, stats);
  kan_fused<<<Bn * TBLK, 256, 0, stream>>>(U, ln_w, ln_b, bw1, sw1, ss1, bw2,
                                           sw2, ss2, stats, out);
}

// Round 2
// 250.007 us; speedup vs baseline: 11.7236x; 11.7236x over previous
//
#include <hip/hip_runtime.h>
#include <math.h>

namespace {

constexpr int Bn = 64;    // batch
constexpr int Cn = 128;   // channels
constexpr int Tn = 512;   // time
constexpr int Hn = 256;   // hidden
constexpr int MROWS = 32; // t-rows per block
constexpr int TBLK = Tn / MROWS;      // 16
constexpr int K1 = Cn * 9;            // 1152
constexpr int K2 = Hn * 9;            // 2304
constexpr int KCP = 296;              // LDS act row stride (288 + 8 pad)
constexpr float LN_EPS = 1e-5f;

typedef __attribute__((ext_vector_type(8))) short short8;
typedef __attribute__((ext_vector_type(4))) float f32x4;

// fp32 -> bf16 bits, round-to-nearest-even
__device__ __forceinline__ unsigned short f2bf(float f) {
  unsigned int u = __builtin_bit_cast(unsigned int, f);
  u = (u + 0x7fffu + ((u >> 16) & 1u)) >> 16;
  return (unsigned short)u;
}

// Cubic B-spline bases on uniform grid g[j] = 0.4*(j-3) - 1, j=0..11.
// Matches the reference recursion exactly.
__device__ __forceinline__ void bspline8(float x, float bs[8]) {
  float g[12];
#pragma unroll
  for (int j = 0; j < 12; ++j) g[j] = (float)(j - 3) * 0.4f - 1.0f;
  float b0[11];
#pragma unroll
  for (int j = 0; j < 11; ++j) b0[j] = (x >= g[j] && x < g[j + 1]) ? 1.0f : 0.0f;
  float b1[10];
#pragma unroll
  for (int j = 0; j < 10; ++j)
    b1[j] = (x - g[j]) * (1.0f / (g[j + 1] - g[j])) * b0[j] +
            (g[j + 2] - x) * (1.0f / (g[j + 2] - g[j + 1])) * b0[j + 1];
  float b2[9];
#pragma unroll
  for (int j = 0; j < 9; ++j)
    b2[j] = (x - g[j]) * (1.0f / (g[j + 2] - g[j])) * b1[j] +
            (g[j + 3] - x) * (1.0f / (g[j + 3] - g[j + 1])) * b1[j + 1];
#pragma unroll
  for (int j = 0; j < 8; ++j)
    bs[j] = (x - g[j]) * (1.0f / (g[j + 3] - g[j])) * b2[j] +
            (g[j + 4] - x) * (1.0f / (g[j + 4] - g[j + 1])) * b2[j + 1];
}

__device__ __forceinline__ float siluf(float z) {
  return z * (1.0f / (1.0f + expf(-z)));
}

}  // namespace

// ---------------------------------------------------------------------------
// Pack weights to bf16 "extended-K" matrices:
//   W1p[h][c*9+j] = sw1[h][c][j]*ss1[h][c] (j<8), bw1[h][c] (j=8)   [256][1152]
//   W2p[c][h*9+j] likewise                                          [128][2304]
// ---------------------------------------------------------------------------
__global__ __launch_bounds__(256) void kan_pack(
    const float* __restrict__ bw1, const float* __restrict__ sw1,
    const float* __restrict__ ss1, const float* __restrict__ bw2,
    const float* __restrict__ sw2, const float* __restrict__ ss2,
    unsigned short* __restrict__ W1p, unsigned short* __restrict__ W2p) {
  int idx = blockIdx.x * 256 + threadIdx.x;  // 0 .. 65535
  if (idx < Hn * Cn) {
    const int o = idx >> 7, i = idx & 127;  // h, c
    const float* sp = sw1 + ((size_t)o * Cn + i) * 8;
    const float sc = ss1[o * Cn + i];
    unsigned short* dst = W1p + (size_t)o * K1 + i * 9;
#pragma unroll
    for (int j = 0; j < 8; ++j) dst[j] = f2bf(sp[j] * sc);
    dst[8] = f2bf(bw1[o * Cn + i]);
  } else {
    idx -= Hn * Cn;
    const int o = idx >> 8, i = idx & 255;  // c, h
    const float* sp = sw2 + ((size_t)o * Hn + i) * 8;
    const float sc = ss2[o * Hn + i];
    unsigned short* dst = W2p + (size_t)o * K2 + i * 9;
#pragma unroll
    for (int j = 0; j < 8; ++j) dst[j] = f2bf(sp[j] * sc);
    dst[8] = f2bf(bw2[o * Hn + i]);
  }
}

// ---------------------------------------------------------------------------
// Per-batch mean / rstd over all C*T elements.
// ---------------------------------------------------------------------------
__global__ __launch_bounds__(256) void kan_stats(const float* __restrict__ U,
                                                 float* __restrict__ stats) {
  const int b = blockIdx.x;
  const float* p = U + (size_t)b * (Cn * Tn);
  float s = 0.f, s2 = 0.f;
  for (int i = threadIdx.x; i < Cn * Tn; i += 256) {
    float v = p[i];
    s += v;
    s2 += v * v;
  }
#pragma unroll
  for (int off = 32; off > 0; off >>= 1) {
    s += __shfl_down(s, off);
    s2 += __shfl_down(s2, off);
  }
  __shared__ float red[2][4];
  if ((threadIdx.x & 63) == 0) {
    red[0][threadIdx.x >> 6] = s;
    red[1][threadIdx.x >> 6] = s2;
  }
  __syncthreads();
  if (threadIdx.x == 0) {
    float ts = red[0][0] + red[0][1] + red[0][2] + red[0][3];
    float ts2 = red[1][0] + red[1][1] + red[1][2] + red[1][3];
    const float inv_n = 1.0f / (float)(Cn * Tn);
    float mean = ts * inv_n;
    float var = ts2 * inv_n - mean * mean;
    stats[2 * b + 0] = mean;
    stats[2 * b + 1] = rsqrtf(var + LN_EPS);
  }
}

// ---------------------------------------------------------------------------
// Fused LN -> KAN1 (MFMA) -> KAN2 (MFMA) -> residual.
// Block = 256 threads (4 waves), 32 t-rows of one batch.
// ---------------------------------------------------------------------------
__global__ __launch_bounds__(256) void kan_fused(
    const float* __restrict__ U, const float* __restrict__ ln_w,
    const float* __restrict__ ln_b, const unsigned short* __restrict__ W1p,
    const unsigned short* __restrict__ W2p, const float* __restrict__ stats,
    float* __restrict__ out) {
  __shared__ unsigned short s_act[MROWS][KCP];  // 18.9 KB, bf16 act chunk
  __shared__ float s_h1[MROWS][Hn + 1];         // 32.9 KB, layer-1 output

  const int tid = threadIdx.x;
  const int b = blockIdx.x / TBLK;
  const int t0 = (blockIdx.x % TBLK) * MROWS;
  const float mean = stats[2 * b + 0];
  const float rstd = stats[2 * b + 1];

  const int w = tid >> 6;        // wave 0..3
  const int l = tid & 63;        // lane
  const int lo = l & 15;
  const int hi = l >> 4;

  // ================= Layer 1: M=32, N=256, K=1152 (4 chunks of 32 c) =======
  f32x4 acc1[2][4] = {};
  for (int chunk = 0; chunk < 4; ++chunk) {
    const int c0 = chunk * 32;
    // ---- act1 chunk: LN + bspline + silu -> s_act (bf16) ----
#pragma unroll
    for (int p = 0; p < 4; ++p) {
      const int e = tid + p * 256;
      const int cl = e >> 5;          // 0..31
      const int row = e & 31;         // t-row
      const int c = c0 + cl;
      const int t = t0 + row;
      const float u = U[((size_t)b * Cn + c) * Tn + t];
      const float z = (u - mean) * rstd * ln_w[t * Cn + c] + ln_b[t * Cn + c];
      float bs[8];
      bspline8(z, bs);
      unsigned short* dst = &s_act[row][cl * 9];
#pragma unroll
      for (int j = 0; j < 8; ++j) dst[j] = f2bf(bs[j]);
      dst[8] = f2bf(siluf(z));
    }
    __syncthreads();
    // ---- MFMA over this K-chunk (9 steps of 32) ----
    const int kbase = c0 * 9;
#pragma unroll
    for (int ks = 0; ks < 9; ++ks) {
      const short8 a0 = *(const short8*)&s_act[lo][ks * 32 + hi * 8];
      const short8 a1 = *(const short8*)&s_act[16 + lo][ks * 32 + hi * 8];
      short8 bf[4];
#pragma unroll
      for (int f = 0; f < 4; ++f) {
        const unsigned short* wp =
            W1p + (size_t)(w * 64 + f * 16 + lo) * K1 + kbase + ks * 32 + hi * 8;
        bf[f] = *(const short8*)wp;
      }
#pragma unroll
      for (int f = 0; f < 4; ++f) {
        acc1[0][f] = __builtin_amdgcn_mfma_f32_16x16x32_bf16(a0, bf[f], acc1[0][f], 0, 0, 0);
        acc1[1][f] = __builtin_amdgcn_mfma_f32_16x16x32_bf16(a1, bf[f], acc1[1][f], 0, 0, 0);
      }
    }
    __syncthreads();
  }

  // ---- write h1 to LDS: row = q*16 + hi*4 + r, col = w*64 + f*16 + lo ----
#pragma unroll
  for (int q = 0; q < 2; ++q)
#pragma unroll
    for (int f = 0; f < 4; ++f)
#pragma unroll
      for (int r = 0; r < 4; ++r)
        s_h1[q * 16 + hi * 4 + r][w * 64 + f * 16 + lo] = acc1[q][f][r];
  __syncthreads();

  // ================= Layer 2: M=32, N=128, K=2304 (8 chunks of 32 h) =======
  f32x4 acc2[2][2] = {};
  for (int chunk = 0; chunk < 8; ++chunk) {
    const int h0 = chunk * 32;
    // ---- act2 chunk ----
#pragma unroll
    for (int p = 0; p < 4; ++p) {
      const int e = tid + p * 256;
      const int hl = e >> 5;
      const int row = e & 31;
      const float z = s_h1[row][h0 + hl];
      float bs[8];
      bspline8(z, bs);
      unsigned short* dst = &s_act[row][hl * 9];
#pragma unroll
      for (int j = 0; j < 8; ++j) dst[j] = f2bf(bs[j]);
      dst[8] = f2bf(siluf(z));
    }
    __syncthreads();
    // ---- MFMA ----
    const int kbase = h0 * 9;
#pragma unroll
    for (int ks = 0; ks < 9; ++ks) {
      const short8 a0 = *(const short8*)&s_act[lo][ks * 32 + hi * 8];
      const short8 a1 = *(const short8*)&s_act[16 + lo][ks * 32 + hi * 8];
      short8 bf[2];
#pragma unroll
      for (int f = 0; f < 2; ++f) {
        const unsigned short* wp =
            W2p + (size_t)(w * 32 + f * 16 + lo) * K2 + kbase + ks * 32 + hi * 8;
        bf[f] = *(const short8*)wp;
      }
#pragma unroll
      for (int f = 0; f < 2; ++f) {
        acc2[0][f] = __builtin_amdgcn_mfma_f32_16x16x32_bf16(a0, bf[f], acc2[0][f], 0, 0, 0);
        acc2[1][f] = __builtin_amdgcn_mfma_f32_16x16x32_bf16(a1, bf[f], acc2[1][f], 0, 0, 0);
      }
    }
    __syncthreads();
  }

  // ================= Epilogue: residual + store =================
#pragma unroll
  for (int q = 0; q < 2; ++q)
#pragma unroll
    for (int f = 0; f < 2; ++f) {
      const int c = w * 32 + f * 16 + lo;
      const size_t base = ((size_t)b * Cn + c) * Tn + t0 + q * 16 + hi * 4;
      const float4 uin = *(const float4*)(U + base);
      float4 o;
      o.x = uin.x + acc2[q][f][0];
      o.y = uin.y + acc2[q][f][1];
      o.z = uin.z + acc2[q][f][2];
      o.w = uin.w + acc2[q][f][3];
      *(float4*)(out + base) = o;
    }
}

extern "C" void kernel_launch(void* const* d_in, const int* in_sizes, int n_in,
                              void* d_out, int out_size, void* d_ws,
                              size_t ws_size, hipStream_t stream) {
  const float* U = (const float*)d_in[0];
  const float* ln_w = (const float*)d_in[1];
  const float* ln_b = (const float*)d_in[2];
  const float* bw1 = (const float*)d_in[3];
  const float* sw1 = (const float*)d_in[4];
  const float* ss1 = (const float*)d_in[5];
  const float* bw2 = (const float*)d_in[6];
  const float* sw2 = (const float*)d_in[7];
  const float* ss2 = (const float*)d_in[8];
  float* out = (float*)d_out;

  float* stats = (float*)d_ws;  // 128 floats
  unsigned short* W1p = (unsigned short*)((char*)d_ws + 1024);
  unsigned short* W2p = W1p + (size_t)Hn * K1;  // after 256*1152

  kan_pack<<<256, 256, 0, stream>>>(bw1, sw1, ss1, bw2, sw2, ss2, W1p, W2p);
  kan_stats<<<Bn, 256, 0, stream>>>(U, stats);
  kan_fused<<<Bn * TBLK, 256, 0, stream>>>(U, ln_w, ln_b, W1p, W2p, stats, out);
}

// Round 3
// 124.109 us; speedup vs baseline: 23.6161x; 2.0144x over previous
//
#include <hip/hip_runtime.h>
#include <math.h>

namespace {

constexpr int Bn = 64;   // batch
constexpr int Cn = 128;  // channels
constexpr int Tn = 512;  // time
constexpr int Hn = 256;  // hidden
constexpr int MR = 64;   // t-rows per block
constexpr int TB = Tn / MR;  // 8 tiles per batch -> grid 512
constexpr int K1 = Cn * 9;   // 1152
constexpr int K2 = Hn * 9;   // 2304
constexpr int KSS = 296;     // act buf row stride in shorts (592B, 16B aligned, 2-way banks)
constexpr int HS = 258;      // h1 row stride in floats (free 2-way banks)
constexpr float LN_EPS = 1e-5f;

typedef __attribute__((ext_vector_type(8))) short short8;
typedef __attribute__((ext_vector_type(4))) float f32x4;

// fp32 -> bf16 bits, round-to-nearest-even
__device__ __forceinline__ unsigned short f2bf(float f) {
  unsigned int u = __builtin_bit_cast(unsigned int, f);
  u = (u + 0x7fffu + ((u >> 16) & 1u)) >> 16;
  return (unsigned short)u;
}

// Closed-form uniform cubic B-spline: grid g[j] = 0.4*(j-3) - 1.
// Cell i = floor((z+2.2)/0.4); nonzero bases j = i-3..i with the standard
// cardinal cubic weights. Identical (up to fp rounding) to the reference
// recursion, including the half-open [g_i, g_{i+1}) convention and the
// all-zero result outside [-2.2, 2.2).
// Writes silu(z) to slot 8*32+feat and the 4 basis values to (j*32+feat);
// slots must be pre-zeroed (done wave-locally, so no barrier needed).
__device__ __forceinline__ void emit_act(float z, unsigned short* __restrict__ bufrow,
                                         int feat) {
  const float e = __expf(-z);
  const float sil = z * __builtin_amdgcn_rcpf(1.0f + e);
  bufrow[256 + feat] = f2bf(sil);  // k-slot 8 = silu (pairs with base_w)
  const float p = z * 2.5f + 5.5f;
  const float fi = floorf(p);
  const int i = (int)fi;
  if (i >= 0 && i <= 10) {
    const float u = p - fi;
    const float u2 = u * u, u3 = u2 * u, t = 1.0f - u;
    const float w0 = t * t * t * (1.0f / 6.0f);                          // j=i-3
    const float w1 = (3.0f * u3 - 6.0f * u2 + 4.0f) * (1.0f / 6.0f);     // j=i-2
    const float w2 = (-3.0f * u3 + 3.0f * u2 + 3.0f * u + 1.0f) * (1.0f / 6.0f);  // j=i-1
    const float w3 = u3 * (1.0f / 6.0f);                                 // j=i
    if (i >= 3) bufrow[(i - 3) * 32 + feat] = f2bf(w0);
    if (i >= 2 && i <= 9) bufrow[(i - 2) * 32 + feat] = f2bf(w1);
    if (i >= 1 && i <= 8) bufrow[(i - 1) * 32 + feat] = f2bf(w2);
    if (i <= 7) bufrow[i * 32 + feat] = f2bf(w3);
  }
}

}  // namespace

// ---------------------------------------------------------------------------
// Prep: blocks 0..255 pack weights (bf16, chunked k-layout: k = chunk*288 +
// j*32 + featLocal); blocks 256..511 compute deterministic per-batch partial
// sums (4 partials per batch) for LN stats.
// ---------------------------------------------------------------------------
__global__ __launch_bounds__(256) void kan_prep(
    const float* __restrict__ U, const float* __restrict__ bw1,
    const float* __restrict__ sw1, const float* __restrict__ ss1,
    const float* __restrict__ bw2, const float* __restrict__ sw2,
    const float* __restrict__ ss2, unsigned short* __restrict__ W1p,
    unsigned short* __restrict__ W2p, float* __restrict__ stats) {
  __shared__ float red[2][4];
  const int blk = blockIdx.x;
  if (blk < 256) {
    int idx = blk * 256 + threadIdx.x;  // 0..65535
    if (idx < Hn * Cn) {
      const int h = idx >> 7, c = idx & 127;
      const float* sp = sw1 + ((size_t)h * Cn + c) * 8;
      const float sc = ss1[h * Cn + c];
      unsigned short* dst = W1p + (size_t)h * K1 + (c >> 5) * 288 + (c & 31);
#pragma unroll
      for (int j = 0; j < 8; ++j) dst[j * 32] = f2bf(sp[j] * sc);
      dst[8 * 32] = f2bf(bw1[h * Cn + c]);
    } else {
      idx -= Hn * Cn;
      const int c = idx >> 8, h = idx & 255;
      const float* sp = sw2 + ((size_t)c * Hn + h) * 8;
      const float sc = ss2[c * Hn + h];
      unsigned short* dst = W2p + (size_t)c * K2 + (h >> 5) * 288 + (h & 31);
#pragma unroll
      for (int j = 0; j < 8; ++j) dst[j * 32] = f2bf(sp[j] * sc);
      dst[8 * 32] = f2bf(bw2[c * Hn + h]);
    }
  } else {
    const int sblk = blk - 256;
    const int b = sblk >> 2, q = sblk & 3;
    const float4* p =
        (const float4*)(U + (size_t)b * (Cn * Tn) + q * (Cn * Tn / 4));
    float s = 0.f, s2 = 0.f;
#pragma unroll 4
    for (int i = threadIdx.x; i < (Cn * Tn / 4) / 4; i += 256) {
      const float4 v = p[i];
      s += v.x + v.y + v.z + v.w;
      s2 += v.x * v.x + v.y * v.y + v.z * v.z + v.w * v.w;
    }
#pragma unroll
    for (int off = 32; off > 0; off >>= 1) {
      s += __shfl_down(s, off);
      s2 += __shfl_down(s2, off);
    }
    if ((threadIdx.x & 63) == 0) {
      red[0][threadIdx.x >> 6] = s;
      red[1][threadIdx.x >> 6] = s2;
    }
    __syncthreads();
    if (threadIdx.x == 0) {
      stats[b * 8 + q * 2 + 0] = red[0][0] + red[0][1] + red[0][2] + red[0][3];
      stats[b * 8 + q * 2 + 1] = red[1][0] + red[1][1] + red[1][2] + red[1][3];
    }
  }
}

// ---------------------------------------------------------------------------
// Fused LN -> KAN1 -> KAN2 -> residual. 1024 threads (16 waves), 64 t-rows.
// Double-buffered bf16 act chunks (32 feats x 9 k-slots, k-major [j][feat]);
// one barrier per chunk; act(k+1) VALU overlaps MFMA(k) + weight loads.
// ---------------------------------------------------------------------------
__global__ __launch_bounds__(1024, 4) void kan_fused(
    const float* __restrict__ U, const float* __restrict__ ln_w,
    const float* __restrict__ ln_b, const unsigned short* __restrict__ W1p,
    const unsigned short* __restrict__ W2p, const float* __restrict__ stats,
    float* __restrict__ out) {
  __shared__ unsigned short s_buf[2][MR * KSS];  // 2 x 37888 B
  __shared__ float s_h1[MR * HS];                // 66048 B

  const int tid = threadIdx.x;
  const int b = blockIdx.x / TB;
  const int t0 = (blockIdx.x % TB) * MR;

  const float* sp = stats + b * 8;
  const float ssum = sp[0] + sp[2] + sp[4] + sp[6];
  const float ssq = sp[1] + sp[3] + sp[5] + sp[7];
  const float inv_n = 1.0f / (float)(Cn * Tn);
  const float mean = ssum * inv_n;
  const float rstd = rsqrtf(ssq * inv_n - mean * mean + LN_EPS);

  const int w = tid >> 6;   // wave 0..15
  const int l = tid & 63;   // lane
  const int lo = l & 15;
  const int hi = l >> 4;
  const int feat = tid & 31;
  const int row0 = tid >> 5;  // 0..31 (rows row0 and row0+32)

  const short8 zz = {0, 0, 0, 0, 0, 0, 0, 0};

  // -------- zero (wave-local rows) + act for layer-1 chunk -> nbuf --------
  auto zero_rows = [&](unsigned short* nbuf) {
#pragma unroll
    for (int it = 0; it < 3; ++it) {
      const int i = l + it * 64;
      if (i < 148) {
        const int rr = i / 37;
        const int off = i - rr * 37;
        const int row = 2 * w + (rr & 1) + (rr >> 1) * 32;
        *(short8*)&nbuf[row * KSS + off * 8] = zz;
      }
    }
  };
  auto act1 = [&](int chunk, unsigned short* nbuf) {
    zero_rows(nbuf);
#pragma unroll
    for (int pp = 0; pp < 2; ++pp) {
      const int row = row0 + pp * 32;
      const int t = t0 + row;
      const int c = chunk * 32 + feat;
      const float uv = U[((size_t)b * Cn + c) * Tn + t];
      const float z = (uv - mean) * rstd * ln_w[t * Cn + c] + ln_b[t * Cn + c];
      emit_act(z, nbuf + row * KSS, feat);
    }
  };
  auto act2 = [&](int chunk, unsigned short* nbuf) {
    zero_rows(nbuf);
#pragma unroll
    for (int pp = 0; pp < 2; ++pp) {
      const int row = row0 + pp * 32;
      const float z = s_h1[row * HS + chunk * 32 + feat];
      emit_act(z, nbuf + row * KSS, feat);
    }
  };

  // ==================== Layer 1: M=64, N=256, K=1152 ====================
  f32x4 acc1[4] = {};  // 4 m-tiles x (16 cols: n = w*16+lo)
  act1(0, s_buf[0]);
  __syncthreads();
  for (int k = 0; k < 4; ++k) {
    const unsigned short* cur = s_buf[k & 1];
    unsigned short* nxt = s_buf[(k + 1) & 1];
    const unsigned short* wb =
        W1p + (size_t)(w * 16 + lo) * K1 + k * 288 + hi * 8;
    short8 bnext = *(const short8*)wb;  // ks = 0
    if (k < 3) act1(k + 1, nxt);        // VALU overlaps weight loads / MFMA
#pragma unroll
    for (int ks = 0; ks < 9; ++ks) {
      const short8 bcur = bnext;
      if (ks < 8) bnext = *(const short8*)(wb + (ks + 1) * 32);
      short8 a[4];
#pragma unroll
      for (int q = 0; q < 4; ++q)
        a[q] = *(const short8*)&cur[(q * 16 + lo) * KSS + ks * 32 + hi * 8];
#pragma unroll
      for (int q = 0; q < 4; ++q)
        acc1[q] =
            __builtin_amdgcn_mfma_f32_16x16x32_bf16(a[q], bcur, acc1[q], 0, 0, 0);
    }
    __syncthreads();
  }

  // h1 -> LDS (f32): row = q*16 + hi*4 + r (t-dim), col = w*16 + lo (h-dim)
#pragma unroll
  for (int q = 0; q < 4; ++q)
#pragma unroll
    for (int r = 0; r < 4; ++r)
      s_h1[(q * 16 + hi * 4 + r) * HS + w * 16 + lo] = acc1[q][r];
  __syncthreads();

  // ==================== Layer 2: M=64, N=128, K=2304 ====================
  const int ng = w & 7;   // n-group: cols ng*16 + lo
  const int mh = w >> 3;  // m-half: rows mh*32 + ...
  f32x4 acc2[2] = {};
  act2(0, s_buf[0]);
  __syncthreads();
  for (int k = 0; k < 8; ++k) {
    const unsigned short* cur = s_buf[k & 1];
    unsigned short* nxt = s_buf[(k + 1) & 1];
    const unsigned short* wb =
        W2p + (size_t)(ng * 16 + lo) * K2 + k * 288 + hi * 8;
    short8 bnext = *(const short8*)wb;
    if (k < 7) act2(k + 1, nxt);
#pragma unroll
    for (int ks = 0; ks < 9; ++ks) {
      const short8 bcur = bnext;
      if (ks < 8) bnext = *(const short8*)(wb + (ks + 1) * 32);
      short8 a[2];
#pragma unroll
      for (int q = 0; q < 2; ++q)
        a[q] = *(const short8*)&cur[(mh * 32 + q * 16 + lo) * KSS + ks * 32 +
                                    hi * 8];
#pragma unroll
      for (int q = 0; q < 2; ++q)
        acc2[q] =
            __builtin_amdgcn_mfma_f32_16x16x32_bf16(a[q], bcur, acc2[q], 0, 0, 0);
    }
    __syncthreads();
  }

  // ==================== Epilogue: residual + store ====================
  const int c = ng * 16 + lo;
#pragma unroll
  for (int q = 0; q < 2; ++q) {
    const int trow = mh * 32 + q * 16 + hi * 4;
    const size_t base = ((size_t)b * Cn + c) * Tn + t0 + trow;
    const float4 uin = *(const float4*)(U + base);
    float4 o;
    o.x = uin.x + acc2[q][0];
    o.y = uin.y + acc2[q][1];
    o.z = uin.z + acc2[q][2];
    o.w = uin.w + acc2[q][3];
    *(float4*)(out + base) = o;
  }
}

extern "C" void kernel_launch(void* const* d_in, const int* in_sizes, int n_in,
                              void* d_out, int out_size, void* d_ws,
                              size_t ws_size, hipStream_t stream) {
  const float* U = (const float*)d_in[0];
  const float* ln_w = (const float*)d_in[1];
  const float* ln_b = (const float*)d_in[2];
  const float* bw1 = (const float*)d_in[3];
  const float* sw1 = (const float*)d_in[4];
  const float* ss1 = (const float*)d_in[5];
  const float* bw2 = (const float*)d_in[6];
  const float* sw2 = (const float*)d_in[7];
  const float* ss2 = (const float*)d_in[8];
  float* out = (float*)d_out;

  float* stats = (float*)d_ws;  // 64*8 floats
  unsigned short* W1p = (unsigned short*)((char*)d_ws + 4096);
  unsigned short* W2p = W1p + (size_t)Hn * K1;

  kan_prep<<<512, 256, 0, stream>>>(U, bw1, sw1, ss1, bw2, sw2, ss2, W1p, W2p,
                                    stats);
  kan_fused<<<Bn * TB, 1024, 0, stream>>>(U, ln_w, ln_b, W1p, W2p, stats, out);
}